// Round 8
// baseline (213.180 us; speedup 1.0000x reference)
//
#include <hip/hip_runtime.h>
#include <hip/hip_bf16.h>
#include <math.h>

#define N_ROI 8192
#define C_IN  1024
#define HIDD  256
#define FGD   64
#define CLSD  128
#define INV_TAU 5.0f
#define SCALE_LOG2E 7.2134752f   // 5 * log2(e)
#define LN2F 0.69314718f

using frag_ab = __attribute__((ext_vector_type(8))) short;   // 8 bf16 = 4 VGPRs
using f32x16  = __attribute__((ext_vector_type(16))) float;

static __device__ __forceinline__ short f32_to_bf16_bits(float f) {
  unsigned u = __builtin_bit_cast(unsigned, f);
  u = (u + 0x7FFFu + ((u >> 16) & 1u)) >> 16;   // RNE (inputs finite)
  return (short)u;
}
static __device__ __forceinline__ float bf16_bits_to_f32(short b) {
  unsigned u = ((unsigned)(unsigned short)b) << 16;
  return __builtin_bit_cast(float, u);
}
static __device__ __forceinline__ float fast_exp2(float x) {
#if __has_builtin(__builtin_amdgcn_exp2f)
  return __builtin_amdgcn_exp2f(x);
#else
  return exp2f(x);
#endif
}
// async global->LDS, 16B per lane. LDS dest = wave-uniform base + lane*16.
static __device__ __forceinline__ void async_copy16(const void* g, void* l) {
  __builtin_amdgcn_global_load_lds(
      (const __attribute__((address_space(1))) unsigned int*)g,
      (__attribute__((address_space(3))) unsigned int*)l, 16, 0, 0);
}

// ---------------- L1: pack weights + X (fp32 -> bf16 frag order) + zero ----------
// X pack: Xp16[(Mb*32 + c)*1024 + (kh*64+lane)*8 + e] =
//           bf16(X[Mb*32 + (lane&31)][c*32 + kh*16 + (lane>>5)*8 + e])
__global__ __launch_bounds__(256) void pack_zero_kernel(
    const float* __restrict__ X,
    const float* __restrict__ w1f, const float* __restrict__ w1c,
    const float* __restrict__ w2f, const float* __restrict__ w2c,
    short* __restrict__ W1pf, short* __restrict__ W1pc,
    short* __restrict__ W2pf, short* __restrict__ W2pc,
    short* __restrict__ Xp16,
    float* __restrict__ accum, int* __restrict__ cnt,
    float* __restrict__ Vc) {
  int b = blockIdx.x;
  if (b == 280) {
    int t = threadIdx.x;
    if (t < 8) accum[t] = 0.f;
    if (t < 24) cnt[t] = 0;
    for (int q = t; q < 2560; q += 256) Vc[q] = 0.f;
    return;
  }
  if (b >= 281) {                       // X pack: 4096 blocks, (Mb, cpair)
    int b2 = b - 281;
    int Mb = b2 >> 4, cpair = b2 & 15;
    int tid = threadIdx.x;
    int c = cpair * 2 + (tid >> 7);
    int tt = tid & 127;
    int lane = tt & 63, kh = tt >> 6;
    int row = lane & 31, hi = lane >> 5;
    const float* src = X + (size_t)(Mb * 32 + row) * C_IN + c * 32 + kh * 16 + hi * 8;
    float4 v0 = *(const float4*)src;
    float4 v1 = *(const float4*)(src + 4);
    union { short s[8]; uint4 v; } o;
    o.s[0] = f32_to_bf16_bits(v0.x); o.s[1] = f32_to_bf16_bits(v0.y);
    o.s[2] = f32_to_bf16_bits(v0.z); o.s[3] = f32_to_bf16_bits(v0.w);
    o.s[4] = f32_to_bf16_bits(v1.x); o.s[5] = f32_to_bf16_bits(v1.y);
    o.s[6] = f32_to_bf16_bits(v1.z); o.s[7] = f32_to_bf16_bits(v1.w);
    *(uint4*)&Xp16[((size_t)(Mb * 32 + c)) * 1024 + (size_t)tt * 8] = o.v;
    return;
  }
  const float* src; short* dst; int Ksh; int b0;
  if (b < 128)      { src = w1f; dst = W1pf; Ksh = 10; b0 = 0; }
  else if (b < 256) { src = w1c; dst = W1pc; Ksh = 10; b0 = 128; }
  else if (b < 264) { src = w2f; dst = W2pf; Ksh = 8;  b0 = 256; }
  else              { src = w2c; dst = W2pc; Ksh = 8;  b0 = 264; }
  int K = 1 << Ksh;
  int f = (b - b0) * 256 + threadIdx.x;
  int r = f >> (Ksh - 3);
  int c0 = (f & ((K >> 3) - 1)) << 3;
  float4 v0 = *(const float4*)(src + (size_t)r * K + c0);
  float4 v1 = *(const float4*)(src + (size_t)r * K + c0 + 4);
  union { short s[8]; uint4 v; } o;
  o.s[0] = f32_to_bf16_bits(v0.x); o.s[1] = f32_to_bf16_bits(v0.y);
  o.s[2] = f32_to_bf16_bits(v0.z); o.s[3] = f32_to_bf16_bits(v0.w);
  o.s[4] = f32_to_bf16_bits(v1.x); o.s[5] = f32_to_bf16_bits(v1.y);
  o.s[6] = f32_to_bf16_bits(v1.z); o.s[7] = f32_to_bf16_bits(v1.w);
  ((uint4*)dst)[(size_t)((r >> 5) * (K >> 4) + (c0 >> 4)) * 64 +
                ((c0 >> 3) & 1) * 32 + (r & 31)] = o.v;
}

// ---------------- phase-2 helper: gemm2+normalize+pack from LDS H tile ----------
template<int D>
__device__ __forceinline__ void gemm2_from_lds(
    const short* __restrict__ T2,
    const short* __restrict__ W2p, const float* __restrict__ b2,
    short* __restrict__ Zr, float* __restrict__ tii,
    short* __restrict__ T, int gt) {
  int lane = threadIdx.x & 63;
  const frag_ab* Wv = (const frag_ab*)W2p;
  constexpr int NT = D / 32;
  frag_ab a[16];
  #pragma unroll
  for (int kc = 0; kc < 16; ++kc)
    a[kc] = *(const frag_ab*)&T2[(lane & 31) * 264 + kc * 16 + (lane >> 5) * 8];
  f32x16 acc[NT];
  #pragma unroll
  for (int j = 0; j < NT; ++j)
    #pragma unroll
    for (int q = 0; q < 16; ++q) acc[j][q] = 0.f;
  #pragma unroll
  for (int kc = 0; kc < 16; ++kc)
    #pragma unroll
    for (int j = 0; j < NT; ++j)
      acc[j] = __builtin_amdgcn_mfma_f32_32x32x16_bf16(a[kc], Wv[(j * 16 + kc) * 64 + lane], acc[j], 0, 0, 0);
  int c = lane & 31, h = lane >> 5;
  float bb[NT];
  #pragma unroll
  for (int j = 0; j < NT; ++j) bb[j] = b2[j * 32 + c];
  float s1[16];
  #pragma unroll
  for (int r = 0; r < 16; ++r) {
    s1[r] = 0.f;
    #pragma unroll
    for (int j = 0; j < NT; ++j) {
      float v = acc[j][r] + bb[j];
      s1[r] += v * v;
    }
  }
  #pragma unroll
  for (int r = 0; r < 16; ++r)
    #pragma unroll
    for (int m = 1; m < 32; m <<= 1) s1[r] += __shfl_xor(s1[r], m);
  float s2[16];
  #pragma unroll
  for (int r = 0; r < 16; ++r) s2[r] = 0.f;
  #pragma unroll
  for (int j = 0; j < NT; ++j) {
    int cl = j * 32 + c;
    #pragma unroll
    for (int g = 0; g < 4; ++g) {
      short q0, q1, q2, q3;
      #pragma unroll
      for (int e = 0; e < 4; ++e) {
        int r = g * 4 + e;
        float sc = 1.f / fmaxf(sqrtf(s1[r]), 1e-8f);
        short qb = f32_to_bf16_bits((acc[j][r] + bb[j]) * sc);
        float zf = bf16_bits_to_f32(qb);
        s2[r] += zf * zf;
        if (e == 0) q0 = qb; else if (e == 1) q1 = qb; else if (e == 2) q2 = qb; else q3 = qb;
      }
      *(short4*)&T[cl * 36 + 4 * h + 8 * g] = make_short4(q0, q1, q2, q3);
    }
  }
  #pragma unroll
  for (int r = 0; r < 16; ++r)
    #pragma unroll
    for (int m = 1; m < 32; m <<= 1) s2[r] += __shfl_xor(s2[r], m);
  if (c == 0) {
    #pragma unroll
    for (int r = 0; r < 16; ++r)
      tii[gt * 32 + (r & 3) + 8 * (r >> 2) + 4 * h] = s2[r];
  }
  uint4* Zv = (uint4*)Zr;
  #pragma unroll
  for (int k = 0; k < D / 16; ++k) {
    int c0 = (2 * k + h) * 8;
    union { short s[8]; uint4 u; } o;
    #pragma unroll
    for (int e = 0; e < 8; ++e) o.s[e] = T[(c0 + e) * 36 + c];
    Zv[(size_t)(gt * (D / 16) + k) * 64 + h * 32 + c] = o.u;
  }
}

// ---------------- L2: fused MLP — A staged via global_load_lds ring (R6 verified)
__global__ __launch_bounds__(256) void fused_mlp_kernel(
    const short* __restrict__ Xp16,
    const short* __restrict__ W1pf, const short* __restrict__ W1pc,
    const float* __restrict__ b1f, const float* __restrict__ b1c,
    const short* __restrict__ W2pf, const short* __restrict__ W2pc,
    const float* __restrict__ b2f, const float* __restrict__ b2c,
    short* __restrict__ Zrf, short* __restrict__ Zrc,
    float* __restrict__ tiif, float* __restrict__ tiic,
    const int* __restrict__ labels,
    float* __restrict__ Sfg, float* __restrict__ Pfg,
    float* __restrict__ Scls,
    float* __restrict__ pfv, float* __restrict__ nimv,
    int* __restrict__ cnt) {
  __shared__ short ringA[4 * 1024];     // 8 KB: 4-slot A ring (2KB/step)
  __shared__ short T2[32 * 264];        // 16.9 KB row-major H (this head)
  __shared__ short Tw[128 * 36];        // 9.2 KB phase-2 transpose
  int tid = threadIdx.x, lane = tid & 63, wv = tid >> 6;
  int Mb = blockIdx.x, head = blockIdx.y;

  if (head == 0 && tid < 32) {
    int i = Mb * 32 + tid;
    Sfg[i] = 0.f; Pfg[i] = 0.f; Scls[i] = 0.f;
    int l = labels[i];
    pfv[i]  = (l > 0)  ? 1.f : 0.f;
    nimv[i] = (l != -1) ? 1.f : 0.f;
    int b = l + 1; if (b < 0) b = 0; if (b > 21) b = 21;
    atomicAdd(&cnt[b], 1);
  }
  // Drain prologue stores/atomics so vmcnt counting below is uniform & exact.
  __builtin_amdgcn_sched_barrier(0);
  asm volatile("s_waitcnt vmcnt(0)" ::: "memory");
  __builtin_amdgcn_sched_barrier(0);

  const short* Wp = head ? W1pc : W1pf;
  const float* b1 = head ? b1c  : b1f;
  const uint4* Wv4 = (const uint4*)Wp;
  int t127 = tid & 127;                 // waves 2,3 redundantly re-stage (uniform vmcnt)

  frag_ab breg[3][4];                   // 3 W banks = 2-step prefetch
  f32x16 acc[2];
  #pragma unroll
  for (int nt = 0; nt < 2; ++nt)
    #pragma unroll
    for (int q = 0; q < 16; ++q) acc[nt][q] = 0.f;

  auto stageA = [&](int c, int slot) {
    const short* src = Xp16 + ((size_t)(Mb * 32 + c)) * 1024 + (size_t)t127 * 8;
    async_copy16(src, &ringA[slot * 1024 + t127 * 8]);
  };
  auto loadB = [&](int c, int s) {
    #pragma unroll
    for (int kci = 0; kci < 2; ++kci)
      #pragma unroll
      for (int nt = 0; nt < 2; ++nt)
        breg[s][kci * 2 + nt] =
            *(const frag_ab*)&Wv4[(size_t)((wv * 2 + nt) * 64 + c * 2 + kci) * 64 + lane];
  };
  auto domfma = [&](int slot, int bank) {
    frag_ab a0 = *(const frag_ab*)&ringA[slot * 1024 + (0 * 64 + lane) * 8];
    frag_ab a1 = *(const frag_ab*)&ringA[slot * 1024 + (1 * 64 + lane) * 8];
    #pragma unroll
    for (int nt = 0; nt < 2; ++nt)
      acc[nt] = __builtin_amdgcn_mfma_f32_32x32x16_bf16(a0, breg[bank][nt], acc[nt], 0, 0, 0);
    #pragma unroll
    for (int nt = 0; nt < 2; ++nt)
      acc[nt] = __builtin_amdgcn_mfma_f32_32x32x16_bf16(a1, breg[bank][2 + nt], acc[nt], 0, 0, 0);
  };

  // prologue: A 3 slots ahead, B 2 banks ahead
  stageA(0, 0); stageA(1, 1); loadB(0, 0); stageA(2, 2); loadB(1, 1);

  #pragma unroll
  for (int c = 0; c < 32; ++c) {
    if (c < 30)       asm volatile("s_waitcnt vmcnt(5)" ::: "memory");
    else if (c == 30) asm volatile("s_waitcnt vmcnt(4)" ::: "memory");
    else              asm volatile("s_waitcnt vmcnt(0)" ::: "memory");
    __builtin_amdgcn_s_barrier();
    __builtin_amdgcn_sched_barrier(0);
    if (c + 3 < 32) stageA(c + 3, (c + 3) & 3);
    if (c + 2 < 32) loadB(c + 2, (c + 2) % 3);
    domfma(c & 3, c % 3);
  }
  {
    int cl31 = lane & 31, h = lane >> 5;
    #pragma unroll
    for (int nt = 0; nt < 2; ++nt) {
      int gc = wv * 64 + nt * 32 + cl31;
      float bb = b1[gc];
      #pragma unroll
      for (int q = 0; q < 16; ++q) {
        int row = (q & 3) + 8 * (q >> 2) + 4 * h;
        float x = fmaxf(acc[nt][q] + bb, 0.f);
        T2[row * 264 + gc] = f32_to_bf16_bits(x);
      }
    }
  }
  __syncthreads();

  if (wv == 0) {
    if (head == 0)
      gemm2_from_lds<FGD>(T2, W2pf, b2f, Zrf, tiif, Tw, Mb);
    else
      gemm2_from_lds<CLSD>(T2, W2pc, b2c, Zrc, tiic, Tw, Mb);
  }
}

// ---------------- classsum body (merged into loss launch, 1-D grid) --------------
__device__ __forceinline__ void classsum_body(
    const short* __restrict__ Zrc, const int* __restrict__ labels,
    float* __restrict__ Vc, int* __restrict__ sh, int cs) {
  int tid = threadIdx.x;
  int unit = tid >> 7, d = tid & 127;
  int cblk = cs % 5, chunk = cs / 5;
  int c = cblk * 4 + unit + 1;          // class 1..20
  int j0 = chunk * 512;
  int* lidx = sh + unit * 512;
  int* lcnt = sh + 2048 + unit;
  if (d == 0) *lcnt = 0;
  __syncthreads();
  #pragma unroll
  for (int u = 0; u < 4; ++u) {
    int rw = j0 + u * 128 + d;
    if (labels[rw] == c) {
      int k = atomicAdd(lcnt, 1);
      lidx[k] = rw;
    }
  }
  __syncthreads();
  int n = *lcnt;
  int kc = d >> 4, h = (d >> 3) & 1, e = d & 7;
  float acc = 0.f;
  for (int k = 0; k < n; ++k) {
    int rw = lidx[k];
    int jt = rw >> 5, r = rw & 31;
    acc += bf16_bits_to_f32(
        Zrc[((size_t)((jt * 8 + kc) * 64 + h * 32 + r)) * 8 + e]);
  }
  atomicAdd(&Vc[(c - 1) * 128 + d], acc);
}

// ---------------- L3: symmetric-triangle MFMA Gram loss --------------------------
// Gram is symmetric: each 256-row group pair (gi<gj) is computed ONCE; the tile
// e-values feed BOTH row-sums of gi (as before) and column-sums of gj (per-lane
// reduction over the 16 acc rows + shfl_xor(32) + atomics, with i-side masks
// preloaded). Halves MFMA and exp (the dominant pipes). Diagonal group blocks
// (gi==gj) compute the full 8x8 tile grid rows-only. e_ij == e_ji exactly: the
// 5*log2e scale is applied POST-MFMA in f32 (MFMA(a,b) is operand-commutative-
// exact), which is also closer to the fp32 reference than pre-rounded scaling.
template<int D, int MODE, bool COLS>
__device__ __forceinline__ void loss_body(
    const short* __restrict__ Zr,
    const float* __restrict__ maskv,     // pfv (fg) / nimv (cls)
    float* __restrict__ Sg, float* __restrict__ Pg,
    short* __restrict__ smem, int gi, int gj) {
  constexpr int KC = D / 16;              // 4 (fg) or 8 (cls)
  constexpr int JP = 2;
  constexpr int NIT = 4;                  // 8 j-tiles per block
  constexpr int BUFQ = JP * KC * 512;     // shorts per buffer (fg 4096, cls 8192)
  constexpr int LD = BUFQ / 4096;         // async copies per wave per STAGE (1/2)
  int tid = threadIdx.x, lane = tid & 63, wv = tid >> 6;   // wv in 0..7
  int itile = gi * 8 + wv;
  int jt0 = gj * 8;                       // j tile base
  int jlane = lane & 31;
  const frag_ab* Zrv = (const frag_ab*)Zr;

  frag_ab a[KC];
  #pragma unroll
  for (int kc = 0; kc < KC; ++kc)
    a[kc] = Zrv[(itile * KC + kc) * 64 + lane];

  float im[16];                           // i-side mask for column contributions
  if (COLS) {
    #pragma unroll
    for (int r = 0; r < 16; ++r) {
      int row = (r & 3) + 8 * (r >> 2) + 4 * (lane >> 5);
      im[r] = maskv[itile * 32 + row];
    }
  }
  // Pin prologue register loads before the drain so later vmcnt counts are exact.
  __builtin_amdgcn_sched_barrier(0);
  asm volatile("s_waitcnt vmcnt(0)" ::: "memory");
  __builtin_amdgcn_sched_barrier(0);

  short* b0 = smem;
  short* b1 = smem + BUFQ;
  short* b2 = smem + 2 * BUFQ;
  float* maskf = (float*)(smem + 3 * BUFQ);   // 256 floats (gj's 8 tiles)

  // stage j-mask: all 8 waves issue the identical copy (uniform vmcnt, same data)
  async_copy16(maskv + (size_t)jt0 * 32 + (size_t)lane * 4, maskf);

  auto STAGE = [&](short* dst, int t) {
    const short* src = Zr + (size_t)(jt0 + t * JP) * KC * 512;
    #pragma unroll
    for (int u = 0; u < LD; ++u)
      async_copy16(src + (size_t)(u * 512 + tid) * 8, dst + u * 4096 + wv * 512);
  };

  STAGE(b0, 0); STAGE(b1, 1);

  float rowS[16] = {}, rowP[16] = {};
  float cS[8] = {}, cP[8] = {};

  #pragma unroll                           // full unroll: cS/cP indices static
  for (int t = 0; t < NIT; ++t) {
    if (t < NIT - 1) {
      if constexpr (LD == 1) asm volatile("s_waitcnt vmcnt(1)" ::: "memory");
      else                   asm volatile("s_waitcnt vmcnt(2)" ::: "memory");
    } else {
      asm volatile("s_waitcnt vmcnt(0)" ::: "memory");
    }
    __builtin_amdgcn_s_barrier();
    __builtin_amdgcn_sched_barrier(0);
    if (t + 2 < NIT) STAGE(b2, t + 2);

    float m0 = maskf[t * 64 + jlane];
    float m1 = maskf[t * 64 + 32 + jlane];
    f32x16 acc0, acc1;
    #pragma unroll
    for (int q = 0; q < 16; ++q) { acc0[q] = 0.f; acc1[q] = 0.f; }
    #pragma unroll
    for (int kc = 0; kc < KC; ++kc) {
      frag_ab bb0 = *(const frag_ab*)&b0[(kc * 64 + lane) * 8];
      frag_ab bb1 = *(const frag_ab*)&b0[((KC + kc) * 64 + lane) * 8];
      acc0 = __builtin_amdgcn_mfma_f32_32x32x16_bf16(a[kc], bb0, acc0, 0, 0, 0);
      acc1 = __builtin_amdgcn_mfma_f32_32x32x16_bf16(a[kc], bb1, acc1, 0, 0, 0);
    }
    #pragma unroll
    for (int rr = 0; rr < 16; ++rr) {
      float e0 = fast_exp2(acc0[rr] * SCALE_LOG2E);
      float e1 = fast_exp2(acc1[rr] * SCALE_LOG2E);
      if (MODE == 0) {
        rowS[rr] += e0 + e1;
        rowP[rr] = fmaf(m0, e0, fmaf(m1, e1, rowP[rr]));
      } else {
        rowS[rr] = fmaf(m1, e1, fmaf(m0, e0, rowS[rr]));
      }
      if (COLS) {
        if (MODE == 0) {
          cS[2 * t]     += e0;
          cS[2 * t + 1] += e1;
          cP[2 * t]     = fmaf(im[rr], e0, cP[2 * t]);
          cP[2 * t + 1] = fmaf(im[rr], e1, cP[2 * t + 1]);
        } else {
          cS[2 * t]     = fmaf(im[rr], e0, cS[2 * t]);
          cS[2 * t + 1] = fmaf(im[rr], e1, cS[2 * t + 1]);
        }
      }
    }
    short* tmp = b0; b0 = b1; b1 = b2; b2 = tmp;   // rotate (static post-unroll)
  }

  // row flush (i-tile rows)
  #pragma unroll
  for (int r = 0; r < 16; ++r) {
    float s = rowS[r], p = rowP[r];
    #pragma unroll
    for (int m = 1; m < 32; m <<= 1) {
      s += __shfl_xor(s, m);
      if (MODE == 0) p += __shfl_xor(p, m);
    }
    if ((lane & 31) == 0) {
      int rw = (r & 3) + 8 * (r >> 2) + 4 * (lane >> 5);
      atomicAdd(&Sg[itile * 32 + rw], s);
      if (MODE == 0) atomicAdd(&Pg[itile * 32 + rw], p);
    }
  }
  // column flush (gj's 8 tiles): two lane-halves cover complementary i-rows
  if (COLS) {
    #pragma unroll
    for (int u = 0; u < 8; ++u) {
      float v = cS[u] + __shfl_xor(cS[u], 32);
      float vp = 0.f;
      if (MODE == 0) vp = cP[u] + __shfl_xor(cP[u], 32);
      if (lane < 32) {
        atomicAdd(&Sg[(jt0 + u) * 32 + jlane], v);
        if (MODE == 0) atomicAdd(&Pg[(jt0 + u) * 32 + jlane], vp);
      }
    }
  }
}

__global__ __launch_bounds__(512, 2) void loss_kernel(
    const short* __restrict__ Zrf, const short* __restrict__ Zrc,
    const int* __restrict__ labels,
    const float* __restrict__ pfv, const float* __restrict__ nimv,
    float* __restrict__ Sfg, float* __restrict__ Pfg,
    float* __restrict__ Scls, float* __restrict__ Vc) {
  // 3 x 16 KB rotating buffers (cls size) + mask region = 50 KB
  __shared__ short smem[3 * 8192 + 1024];
  int bx = blockIdx.x;
  if (bx < 80) {                        // merged classsum blocks
    classsum_body(Zrc, labels, Vc, (int*)smem, bx);
    return;
  }
  int li = bx - 80;
  int mode = li & 1;                    // interleave fg/cls for pipe balance
  int p = li >> 1;                      // [0, 528): 32 diag + 496 pairs
  int gi, gj;
  if (p < 32) { gi = p; gj = p; }
  else {
    int q = p - 32;
    gi = 0;
    while (q >= 31 - gi) { q -= 31 - gi; ++gi; }
    gj = gi + 1 + q;
  }
  if (mode == 0) {
    if (gi == gj) loss_body<FGD, 0, false>(Zrf, pfv, Sfg, Pfg, smem, gi, gj);
    else          loss_body<FGD, 0, true >(Zrf, pfv, Sfg, Pfg, smem, gi, gj);
  } else {
    if (gi == gj) loss_body<CLSD, 1, false>(Zrc, nimv, Scls, nullptr, smem, gi, gj);
    else          loss_body<CLSD, 1, true >(Zrc, nimv, Scls, nullptr, smem, gi, gj);
  }
}

// ---------------- L4: per-row losses + weighted reduction + write-out ------------
__global__ __launch_bounds__(256) void finalize_kernel(
    const float* __restrict__ Sfg, const float* __restrict__ Pfg,
    const float* __restrict__ Scls,
    const short* __restrict__ Zrc, const float* __restrict__ Vc,
    const float* __restrict__ tiif, const float* __restrict__ tiic,
    const int* __restrict__ labels, const float* __restrict__ ious,
    int* __restrict__ cnt, float* __restrict__ accum, float* __restrict__ out) {
  int i = blockIdx.x * 256 + threadIdx.x;
  int l = labels[i];
  float iv = ious[i];
  float w = (iv > 0.5f) ? iv : 0.f;
  int cntP = 0;
  #pragma unroll
  for (int b = 2; b <= 21; ++b) cntP += cnt[b];
  int cntNI = N_ROI - cnt[0];
  bool Pi = (l > 0);
  float numF = 0.f, denF = 0.f, numC = 0.f, denC = 0.f;
  float eF = __expf(INV_TAU * tiif[i]);
  float Sf = Sfg[i] - eF;
  float Pf = Pfg[i] - (Pi ? eF : 0.f);
  int nposF = cntP - (Pi ? 1 : 0);
  if (Pi && nposF > 0) {
    float lossF = logf((Sf + 1e-8f) / (Pf + 1e-8f));
    numF = lossF * w; denF = w;
  }
  float tC = INV_TAU * tiic[i];
  float eC = __expf(tC);
  float Sc = Scls[i] - ((l != -1) ? eC : 0.f);
  // SP via class-sum decomposition: z_i . Vc[lab_i] * INV_TAU, minus self sim.
  float SPdot = 0.f;
  if (Pi) {
    const float* V = Vc + (size_t)(l - 1) * 128;
    int jt = i >> 5, r = i & 31;
    #pragma unroll
    for (int kc = 0; kc < 8; ++kc)
      #pragma unroll
      for (int h = 0; h < 2; ++h) {
        frag_ab z = *(const frag_ab*)&Zrc[((size_t)((jt * 8 + kc) * 64 + h * 32 + r)) * 8];
        #pragma unroll
        for (int e = 0; e < 8; ++e)
          SPdot += bf16_bits_to_f32(z[e]) * V[kc * 16 + h * 8 + e];
      }
  }
  float SP = SPdot * INV_TAU - (Pi ? tC : 0.f);
  int nposC = Pi ? (cnt[l + 1] - 1) : 0;
  bool anyv = (cntNI - ((l != -1) ? 1 : 0)) > 0;
  if (Pi && nposC > 0 && anyv) {
    float lse = logf(Sc);
    float lossC = -(SP - (float)nposC * lse) / fmaxf((float)nposC, 1.f);
    numC = lossC * w; denC = w;
  }
  float v0 = numF, v1 = denF, v2 = numC, v3 = denC;
  #pragma unroll
  for (int m = 1; m < 64; m <<= 1) {
    v0 += __shfl_xor(v0, m); v1 += __shfl_xor(v1, m);
    v2 += __shfl_xor(v2, m); v3 += __shfl_xor(v3, m);
  }
  __shared__ float red[4][4];
  int lane = threadIdx.x & 63, wid = threadIdx.x >> 6;
  if (lane == 0) { red[wid][0]=v0; red[wid][1]=v1; red[wid][2]=v2; red[wid][3]=v3; }
  __syncthreads();
  if (threadIdx.x == 0) {
    float s0=0,s1=0,s2=0,s3=0;
    for (int q = 0; q < 4; ++q) { s0+=red[q][0]; s1+=red[q][1]; s2+=red[q][2]; s3+=red[q][3]; }
    atomicAdd(&accum[0], s0); atomicAdd(&accum[1], s1);
    atomicAdd(&accum[2], s2); atomicAdd(&accum[3], s3);
    __threadfence();
    int t = atomicAdd(&cnt[22], 1);
    if (t == 31) {
      __threadfence();
      out[0] = accum[0] / (accum[1] + 1e-8f);
      out[1] = accum[2] / (accum[3] + 1e-12f);
    }
  }
}

extern "C" void kernel_launch(void* const* d_in, const int* in_sizes, int n_in,
                              void* d_out, int out_size, void* d_ws, size_t ws_size,
                              hipStream_t stream) {
  const float* X    = (const float*)d_in[0];
  const int*  labels= (const int*)d_in[1];
  const float* ious = (const float*)d_in[2];
  const float* w1f  = (const float*)d_in[3];
  const float* b1f  = (const float*)d_in[4];
  const float* w2f  = (const float*)d_in[5];
  const float* b2f  = (const float*)d_in[6];
  const float* w1c  = (const float*)d_in[7];
  const float* b1c  = (const float*)d_in[8];
  const float* w2c  = (const float*)d_in[9];
  const float* b2c  = (const float*)d_in[10];
  float* out = (float*)d_out;

  char* w = (char*)d_ws;
  short* W1pf = (short*)w;            w += 524288;
  short* W1pc = (short*)w;            w += 524288;
  short* W2pf = (short*)w;            w += 32768;
  short* W2pc = (short*)w;            w += 65536;
  short* Zrf  = (short*)w;            w += 1048576;
  short* Zrc  = (short*)w;            w += 2097152;
  float* Sfg  = (float*)w;            w += 32768;
  float* Pfg  = (float*)w;            w += 32768;
  float* Scls = (float*)w;            w += 32768;
  float* SPc  = (float*)w;            w += 32768;   // unused (kept for layout)
  float* tiif = (float*)w;            w += 32768;
  float* tiic = (float*)w;            w += 32768;
  float* pfv  = (float*)w;            w += 32768;
  float* nimv = (float*)w;            w += 32768;
  float* ljmv = (float*)w;            w += 32768;   // unused (kept for layout)
  float* accum= (float*)w;            w += 32;
  int*   cnt  = (int*)w;              w += 96;
  float* Vc   = (float*)w;            w += 10240;   // 20 classes x 128 dims f32
  short* Xp16 = (short*)w;            w += 16777216; // X in bf16 frag order
  (void)SPc; (void)ljmv;

  pack_zero_kernel<<<281 + 4096, 256, 0, stream>>>(X, w1f, w1c, w2f, w2c,
                                            W1pf, W1pc, W2pf, W2pc, Xp16,
                                            accum, cnt, Vc);

  fused_mlp_kernel<<<dim3(256, 2), 256, 0, stream>>>(Xp16, W1pf, W1pc, b1f, b1c,
                                            W2pf, W2pc, b2f, b2c,
                                            Zrf, Zrc, tiif, tiic,
                                            labels, Sfg, Pfg, Scls,
                                            pfv, nimv, cnt);

  // 80 classsum blocks + 2 modes x (32 diag + 496 triangle-pair) blocks
  loss_kernel<<<80 + 2 * 528, 512, 0, stream>>>(Zrf, Zrc, labels, pfv, nimv,
                                                Sfg, Pfg, Scls, Vc);

  finalize_kernel<<<N_ROI/256, 256, 0, stream>>>(Sfg, Pfg, Scls, Zrc, Vc,
                                                 tiif, tiic,
                                                 labels, ious, cnt, accum, out);
}

// Round 9
// 195.028 us; speedup vs baseline: 1.0931x; 1.0931x over previous
//
#include <hip/hip_runtime.h>
#include <hip/hip_bf16.h>
#include <math.h>

#define N_ROI 8192
#define C_IN  1024
#define HIDD  256
#define FGD   64
#define CLSD  128
#define INV_TAU 5.0f
#define SCALE_LOG2E 7.2134752f   // 5 * log2(e)
#define LN2F 0.69314718f

using frag_ab = __attribute__((ext_vector_type(8))) short;   // 8 bf16 = 4 VGPRs
using f32x16  = __attribute__((ext_vector_type(16))) float;

static __device__ __forceinline__ short f32_to_bf16_bits(float f) {
  unsigned u = __builtin_bit_cast(unsigned, f);
  u = (u + 0x7FFFu + ((u >> 16) & 1u)) >> 16;   // RNE (inputs finite)
  return (short)u;
}
static __device__ __forceinline__ float bf16_bits_to_f32(short b) {
  unsigned u = ((unsigned)(unsigned short)b) << 16;
  return __builtin_bit_cast(float, u);
}
static __device__ __forceinline__ float fast_exp2(float x) {
#if __has_builtin(__builtin_amdgcn_exp2f)
  return __builtin_amdgcn_exp2f(x);
#else
  return exp2f(x);
#endif
}
// async global->LDS, 16B per lane. LDS dest = wave-uniform base + lane*16.
static __device__ __forceinline__ void async_copy16(const void* g, void* l) {
  __builtin_amdgcn_global_load_lds(
      (const __attribute__((address_space(1))) unsigned int*)g,
      (__attribute__((address_space(3))) unsigned int*)l, 16, 0, 0);
}

// ---------------- L1: pack weights + X (fp32 -> bf16 frag order) + zero ----------
// X pack (COALESCED rewrite of the R6 version; output layout bit-identical):
//   Xp16[(Mb*32+c)*1024 + g*256 + r*8 + e] = bf16(X[Mb*32+r][c*32 + g*8 + e])
// which satisfies the frag-order invariant col=(o>>8)*8+(o&7), row=(o>>3)&31.
// Reads: 4 consecutive lanes cover one row's 128B (coalesced); writes: 16B
// aligned, 4 interleaved contiguous streams per wave.
__global__ __launch_bounds__(256) void pack_zero_kernel(
    const float* __restrict__ X,
    const float* __restrict__ w1f, const float* __restrict__ w1c,
    const float* __restrict__ w2f, const float* __restrict__ w2c,
    short* __restrict__ W1pf, short* __restrict__ W1pc,
    short* __restrict__ W2pf, short* __restrict__ W2pc,
    short* __restrict__ Xp16,
    float* __restrict__ accum, int* __restrict__ cnt,
    float* __restrict__ Vc) {
  int b = blockIdx.x;
  if (b == 280) {
    int t = threadIdx.x;
    if (t < 8) accum[t] = 0.f;
    if (t < 24) cnt[t] = 0;
    for (int q = t; q < 2560; q += 256) Vc[q] = 0.f;
    return;
  }
  if (b >= 281) {                       // X pack: 4096 blocks, (Mb, cpair)
    int b2 = b - 281;
    int Mb = b2 >> 4, cpair = b2 & 15;
    int tid = threadIdx.x;
    int c = cpair * 2 + (tid >> 7);     // two col-tiles per block
    int tt = tid & 127;
    int r = tt >> 2;                    // row 0..31
    int g = tt & 3;                     // col-group 0..3 (8 cols each)
    const float* src = X + (size_t)(Mb * 32 + r) * C_IN + c * 32 + g * 8;
    float4 v0 = *(const float4*)src;
    float4 v1 = *(const float4*)(src + 4);
    union { short s[8]; uint4 v; } o;
    o.s[0] = f32_to_bf16_bits(v0.x); o.s[1] = f32_to_bf16_bits(v0.y);
    o.s[2] = f32_to_bf16_bits(v0.z); o.s[3] = f32_to_bf16_bits(v0.w);
    o.s[4] = f32_to_bf16_bits(v1.x); o.s[5] = f32_to_bf16_bits(v1.y);
    o.s[6] = f32_to_bf16_bits(v1.z); o.s[7] = f32_to_bf16_bits(v1.w);
    *(uint4*)&Xp16[((size_t)(Mb * 32 + c)) * 1024 + g * 256 + r * 8] = o.v;
    return;
  }
  const float* src; short* dst; int Ksh; int b0;
  if (b < 128)      { src = w1f; dst = W1pf; Ksh = 10; b0 = 0; }
  else if (b < 256) { src = w1c; dst = W1pc; Ksh = 10; b0 = 128; }
  else if (b < 264) { src = w2f; dst = W2pf; Ksh = 8;  b0 = 256; }
  else              { src = w2c; dst = W2pc; Ksh = 8;  b0 = 264; }
  int K = 1 << Ksh;
  int f = (b - b0) * 256 + threadIdx.x;
  int r = f >> (Ksh - 3);
  int c0 = (f & ((K >> 3) - 1)) << 3;
  float4 v0 = *(const float4*)(src + (size_t)r * K + c0);
  float4 v1 = *(const float4*)(src + (size_t)r * K + c0 + 4);
  union { short s[8]; uint4 v; } o;
  o.s[0] = f32_to_bf16_bits(v0.x); o.s[1] = f32_to_bf16_bits(v0.y);
  o.s[2] = f32_to_bf16_bits(v0.z); o.s[3] = f32_to_bf16_bits(v0.w);
  o.s[4] = f32_to_bf16_bits(v1.x); o.s[5] = f32_to_bf16_bits(v1.y);
  o.s[6] = f32_to_bf16_bits(v1.z); o.s[7] = f32_to_bf16_bits(v1.w);
  ((uint4*)dst)[(size_t)((r >> 5) * (K >> 4) + (c0 >> 4)) * 64 +
                ((c0 >> 3) & 1) * 32 + (r & 31)] = o.v;
}

// ---------------- phase-2 helper: gemm2+normalize+pack from LDS H tile ----------
template<int D>
__device__ __forceinline__ void gemm2_from_lds(
    const short* __restrict__ T2,
    const short* __restrict__ W2p, const float* __restrict__ b2,
    short* __restrict__ Zr, float* __restrict__ tii,
    short* __restrict__ T, int gt) {
  int lane = threadIdx.x & 63;
  const frag_ab* Wv = (const frag_ab*)W2p;
  constexpr int NT = D / 32;
  frag_ab a[16];
  #pragma unroll
  for (int kc = 0; kc < 16; ++kc)
    a[kc] = *(const frag_ab*)&T2[(lane & 31) * 264 + kc * 16 + (lane >> 5) * 8];
  f32x16 acc[NT];
  #pragma unroll
  for (int j = 0; j < NT; ++j)
    #pragma unroll
    for (int q = 0; q < 16; ++q) acc[j][q] = 0.f;
  #pragma unroll
  for (int kc = 0; kc < 16; ++kc)
    #pragma unroll
    for (int j = 0; j < NT; ++j)
      acc[j] = __builtin_amdgcn_mfma_f32_32x32x16_bf16(a[kc], Wv[(j * 16 + kc) * 64 + lane], acc[j], 0, 0, 0);
  int c = lane & 31, h = lane >> 5;
  float bb[NT];
  #pragma unroll
  for (int j = 0; j < NT; ++j) bb[j] = b2[j * 32 + c];
  float s1[16];
  #pragma unroll
  for (int r = 0; r < 16; ++r) {
    s1[r] = 0.f;
    #pragma unroll
    for (int j = 0; j < NT; ++j) {
      float v = acc[j][r] + bb[j];
      s1[r] += v * v;
    }
  }
  #pragma unroll
  for (int r = 0; r < 16; ++r)
    #pragma unroll
    for (int m = 1; m < 32; m <<= 1) s1[r] += __shfl_xor(s1[r], m);
  float s2[16];
  #pragma unroll
  for (int r = 0; r < 16; ++r) s2[r] = 0.f;
  #pragma unroll
  for (int j = 0; j < NT; ++j) {
    int cl = j * 32 + c;
    #pragma unroll
    for (int g = 0; g < 4; ++g) {
      short q0, q1, q2, q3;
      #pragma unroll
      for (int e = 0; e < 4; ++e) {
        int r = g * 4 + e;
        float sc = 1.f / fmaxf(sqrtf(s1[r]), 1e-8f);
        short qb = f32_to_bf16_bits((acc[j][r] + bb[j]) * sc);
        float zf = bf16_bits_to_f32(qb);
        s2[r] += zf * zf;
        if (e == 0) q0 = qb; else if (e == 1) q1 = qb; else if (e == 2) q2 = qb; else q3 = qb;
      }
      *(short4*)&T[cl * 36 + 4 * h + 8 * g] = make_short4(q0, q1, q2, q3);
    }
  }
  #pragma unroll
  for (int r = 0; r < 16; ++r)
    #pragma unroll
    for (int m = 1; m < 32; m <<= 1) s2[r] += __shfl_xor(s2[r], m);
  if (c == 0) {
    #pragma unroll
    for (int r = 0; r < 16; ++r)
      tii[gt * 32 + (r & 3) + 8 * (r >> 2) + 4 * h] = s2[r];
  }
  uint4* Zv = (uint4*)Zr;
  #pragma unroll
  for (int k = 0; k < D / 16; ++k) {
    int c0 = (2 * k + h) * 8;
    union { short s[8]; uint4 u; } o;
    #pragma unroll
    for (int e = 0; e < 8; ++e) o.s[e] = T[(c0 + e) * 36 + c];
    Zv[(size_t)(gt * (D / 16) + k) * 64 + h * 32 + c] = o.u;
  }
}

// ---------------- L2: fused MLP — A staged via global_load_lds ring (R6 verified,
// 43.4 us measured, 0 bank conflicts — reverted verbatim) ------------------------
__global__ __launch_bounds__(256) void fused_mlp_kernel(
    const short* __restrict__ Xp16,
    const short* __restrict__ W1pf, const short* __restrict__ W1pc,
    const float* __restrict__ b1f, const float* __restrict__ b1c,
    const short* __restrict__ W2pf, const short* __restrict__ W2pc,
    const float* __restrict__ b2f, const float* __restrict__ b2c,
    short* __restrict__ Zrf, short* __restrict__ Zrc,
    float* __restrict__ tiif, float* __restrict__ tiic,
    const int* __restrict__ labels,
    float* __restrict__ Sfg, float* __restrict__ Pfg,
    float* __restrict__ Scls,
    float* __restrict__ pfv, float* __restrict__ nimv,
    int* __restrict__ cnt) {
  __shared__ short ringA[4 * 1024];     // 8 KB: 4-slot A ring (2KB/step)
  __shared__ short T2[32 * 264];        // 16.9 KB row-major H (this head)
  __shared__ short Tw[128 * 36];        // 9.2 KB phase-2 transpose
  int tid = threadIdx.x, lane = tid & 63, wv = tid >> 6;
  int Mb = blockIdx.x, head = blockIdx.y;

  if (head == 0 && tid < 32) {
    int i = Mb * 32 + tid;
    Sfg[i] = 0.f; Pfg[i] = 0.f; Scls[i] = 0.f;
    int l = labels[i];
    pfv[i]  = (l > 0)  ? 1.f : 0.f;
    nimv[i] = (l != -1) ? 1.f : 0.f;
    int b = l + 1; if (b < 0) b = 0; if (b > 21) b = 21;
    atomicAdd(&cnt[b], 1);
  }
  // Drain prologue stores/atomics so vmcnt counting below is uniform & exact.
  __builtin_amdgcn_sched_barrier(0);
  asm volatile("s_waitcnt vmcnt(0)" ::: "memory");
  __builtin_amdgcn_sched_barrier(0);

  const short* Wp = head ? W1pc : W1pf;
  const float* b1 = head ? b1c  : b1f;
  const uint4* Wv4 = (const uint4*)Wp;
  int t127 = tid & 127;                 // waves 2,3 redundantly re-stage (uniform vmcnt)

  frag_ab breg[3][4];                   // 3 W banks = 2-step prefetch
  f32x16 acc[2];
  #pragma unroll
  for (int nt = 0; nt < 2; ++nt)
    #pragma unroll
    for (int q = 0; q < 16; ++q) acc[nt][q] = 0.f;

  auto stageA = [&](int c, int slot) {
    const short* src = Xp16 + ((size_t)(Mb * 32 + c)) * 1024 + (size_t)t127 * 8;
    async_copy16(src, &ringA[slot * 1024 + t127 * 8]);
  };
  auto loadB = [&](int c, int s) {
    #pragma unroll
    for (int kci = 0; kci < 2; ++kci)
      #pragma unroll
      for (int nt = 0; nt < 2; ++nt)
        breg[s][kci * 2 + nt] =
            *(const frag_ab*)&Wv4[(size_t)((wv * 2 + nt) * 64 + c * 2 + kci) * 64 + lane];
  };
  auto domfma = [&](int slot, int bank) {
    frag_ab a0 = *(const frag_ab*)&ringA[slot * 1024 + (0 * 64 + lane) * 8];
    frag_ab a1 = *(const frag_ab*)&ringA[slot * 1024 + (1 * 64 + lane) * 8];
    #pragma unroll
    for (int nt = 0; nt < 2; ++nt)
      acc[nt] = __builtin_amdgcn_mfma_f32_32x32x16_bf16(a0, breg[bank][nt], acc[nt], 0, 0, 0);
    #pragma unroll
    for (int nt = 0; nt < 2; ++nt)
      acc[nt] = __builtin_amdgcn_mfma_f32_32x32x16_bf16(a1, breg[bank][2 + nt], acc[nt], 0, 0, 0);
  };

  // prologue: A 3 slots ahead, B 2 banks ahead
  stageA(0, 0); stageA(1, 1); loadB(0, 0); stageA(2, 2); loadB(1, 1);

  #pragma unroll
  for (int c = 0; c < 32; ++c) {
    if (c < 30)       asm volatile("s_waitcnt vmcnt(5)" ::: "memory");
    else if (c == 30) asm volatile("s_waitcnt vmcnt(4)" ::: "memory");
    else              asm volatile("s_waitcnt vmcnt(0)" ::: "memory");
    __builtin_amdgcn_s_barrier();
    __builtin_amdgcn_sched_barrier(0);
    if (c + 3 < 32) stageA(c + 3, (c + 3) & 3);
    if (c + 2 < 32) loadB(c + 2, (c + 2) % 3);
    domfma(c & 3, c % 3);
  }
  {
    int cl31 = lane & 31, h = lane >> 5;
    #pragma unroll
    for (int nt = 0; nt < 2; ++nt) {
      int gc = wv * 64 + nt * 32 + cl31;
      float bb = b1[gc];
      #pragma unroll
      for (int q = 0; q < 16; ++q) {
        int row = (q & 3) + 8 * (q >> 2) + 4 * h;
        float x = fmaxf(acc[nt][q] + bb, 0.f);
        T2[row * 264 + gc] = f32_to_bf16_bits(x);
      }
    }
  }
  __syncthreads();

  if (wv == 0) {
    if (head == 0)
      gemm2_from_lds<FGD>(T2, W2pf, b2f, Zrf, tiif, Tw, Mb);
    else
      gemm2_from_lds<CLSD>(T2, W2pc, b2c, Zrc, tiic, Tw, Mb);
  }
}

// ---------------- classsum body (merged into loss launch; R7-verified) -----------
__device__ __forceinline__ void classsum_body(
    const short* __restrict__ Zrc, const int* __restrict__ labels,
    float* __restrict__ Vc, int* __restrict__ sh) {
  int tid = threadIdx.x;
  int unit = tid >> 7, d = tid & 127;
  int c = (blockIdx.x - 64) * 4 + unit + 1;   // class 1..20
  int j0 = blockIdx.y * 512;
  int* lidx = sh + unit * 512;
  int* lcnt = sh + 2048 + unit;
  if (d == 0) *lcnt = 0;
  __syncthreads();
  #pragma unroll
  for (int u = 0; u < 4; ++u) {
    int rw = j0 + u * 128 + d;
    if (labels[rw] == c) {
      int k = atomicAdd(lcnt, 1);
      lidx[k] = rw;
    }
  }
  __syncthreads();
  int n = *lcnt;
  int kc = d >> 4, h = (d >> 3) & 1, e = d & 7;
  float acc = 0.f;
  for (int k = 0; k < n; ++k) {
    int rw = lidx[k];
    int jt = rw >> 5, r = rw & 31;
    acc += bf16_bits_to_f32(
        Zrc[((size_t)((jt * 8 + kc) * 64 + h * 32 + r)) * 8 + e]);
  }
  atomicAdd(&Vc[(c - 1) * 128 + d], acc);
}

// ---------------- L3: MFMA Gram loss — full Gram, JP=2, cls Psum removed ---------
// (R6-verified structure: 3 rotating buffers, counted vmcnt, NIT=8.)
template<int D, int MODE, int NJT>
__device__ __forceinline__ void loss_body(
    const short* __restrict__ Zr,
    const float* __restrict__ maskv,
    float* __restrict__ Sg, float* __restrict__ Pg,
    short* __restrict__ smem) {
  constexpr int KC = D / 16;              // 4 (fg) or 8 (cls)
  constexpr int JP = 2;
  constexpr int NIT = NJT / JP;           // 8
  constexpr int BUFQ = JP * KC * 512;     // shorts per buffer (fg 4096, cls 8192)
  constexpr int LD = BUFQ / 4096;         // async copies per wave per STAGE (1/2)
  int tid = threadIdx.x, lane = tid & 63, wv = tid >> 6;   // wv in 0..7
  int itile = (blockIdx.x >> 1) * 8 + wv;
  int jt0 = blockIdx.y * NJT;
  int jlane = lane & 31;
  const frag_ab* Zrv = (const frag_ab*)Zr;

  // A fragments (rescaled to log2-domain)
  frag_ab a[KC];
  #pragma unroll
  for (int kc = 0; kc < KC; ++kc) {
    frag_ab t = Zrv[(itile * KC + kc) * 64 + lane];
    #pragma unroll
    for (int e = 0; e < 8; ++e)
      t[e] = f32_to_bf16_bits(bf16_bits_to_f32(t[e]) * SCALE_LOG2E);
    a[kc] = t;
  }
  // Pin prologue register loads before the drain so later vmcnt counts are exact.
  __builtin_amdgcn_sched_barrier(0);
  asm volatile("s_waitcnt vmcnt(0)" ::: "memory");
  __builtin_amdgcn_sched_barrier(0);

  short* b0 = smem;
  short* b1 = smem + BUFQ;
  short* b2 = smem + 2 * BUFQ;
  float* maskf = (float*)(smem + 3 * BUFQ);   // NJT*32 = 512 floats

  // stage mask: exactly 1 global_load_lds per wave (waves 2-7 redundant)
  async_copy16(maskv + jt0 * 32 + (size_t)(tid & 127) * 4,
               maskf + (wv & 1) * 256);

  auto STAGE = [&](short* dst, int it) {
    const short* src = Zr + (size_t)(jt0 + it * JP) * KC * 512;
    #pragma unroll
    for (int u = 0; u < LD; ++u)
      async_copy16(src + (size_t)(u * 512 + tid) * 8, dst + u * 4096 + wv * 512);
  };

  STAGE(b0, 0); STAGE(b1, 1);

  float Ssum[16] = {}, Psum[16] = {};

  #pragma unroll 1
  for (int t = 0; t < NIT; ++t) {
    if (t < NIT - 1) {
      if constexpr (LD == 1) asm volatile("s_waitcnt vmcnt(1)" ::: "memory");
      else                   asm volatile("s_waitcnt vmcnt(2)" ::: "memory");
    } else {
      asm volatile("s_waitcnt vmcnt(0)" ::: "memory");
    }
    __builtin_amdgcn_s_barrier();
    __builtin_amdgcn_sched_barrier(0);
    if (t + 2 < NIT) STAGE(b2, t + 2);

    float m0 = maskf[t * 64 + jlane];
    float m1 = maskf[t * 64 + 32 + jlane];
    f32x16 acc0, acc1;
    #pragma unroll
    for (int q = 0; q < 16; ++q) { acc0[q] = 0.f; acc1[q] = 0.f; }
    #pragma unroll
    for (int kc = 0; kc < KC; ++kc) {
      frag_ab bb0 = *(const frag_ab*)&b0[(kc * 64 + lane) * 8];
      frag_ab bb1 = *(const frag_ab*)&b0[((KC + kc) * 64 + lane) * 8];
      acc0 = __builtin_amdgcn_mfma_f32_32x32x16_bf16(a[kc], bb0, acc0, 0, 0, 0);
      acc1 = __builtin_amdgcn_mfma_f32_32x32x16_bf16(a[kc], bb1, acc1, 0, 0, 0);
    }
    #pragma unroll
    for (int rr = 0; rr < 16; ++rr) {
      float e0 = fast_exp2(acc0[rr]);
      float e1 = fast_exp2(acc1[rr]);
      if (MODE == 0) {
        Ssum[rr] += e0 + e1;
        Psum[rr] = fmaf(m0, e0, fmaf(m1, e1, Psum[rr]));
      } else {
        Ssum[rr] = fmaf(m1, e1, fmaf(m0, e0, Ssum[rr]));
      }
    }
    short* tmp = b0; b0 = b1; b1 = b2; b2 = tmp;   // rotate
  }

  #pragma unroll
  for (int r = 0; r < 16; ++r) {
    float s = Ssum[r], p = Psum[r];
    #pragma unroll
    for (int m = 1; m < 32; m <<= 1) {
      s += __shfl_xor(s, m);
      if (MODE == 0) p += __shfl_xor(p, m);
    }
    if ((lane & 31) == 0) {
      int rw = (r & 3) + 8 * (r >> 2) + 4 * (lane >> 5);
      atomicAdd(&Sg[itile * 32 + rw], s);
      if (MODE == 0) atomicAdd(&Pg[itile * 32 + rw], p);
    }
  }
}

__global__ __launch_bounds__(512, 2) void loss_kernel(
    const short* __restrict__ Zrf, const short* __restrict__ Zrc,
    const int* __restrict__ labels,
    const float* __restrict__ pfv, const float* __restrict__ nimv,
    float* __restrict__ Sfg, float* __restrict__ Pfg,
    float* __restrict__ Scls, float* __restrict__ Vc) {
  // 3 x 16 KB rotating buffers (cls size) + mask region = 50 KB
  __shared__ short smem[3 * 8192 + 1024];
  if (blockIdx.x >= 64) {               // merged classsum blocks (x=64..68)
    classsum_body(Zrc, labels, Vc, (int*)smem);
    return;
  }
  if ((blockIdx.x & 1) == 0)
    loss_body<FGD, 0, 16>(Zrf, pfv, Sfg, Pfg, smem);
  else
    loss_body<CLSD, 1, 16>(Zrc, nimv, Scls, nullptr, smem);
}

// ---------------- L4: per-row losses + weighted reduction + write-out ------------
__global__ __launch_bounds__(256) void finalize_kernel(
    const float* __restrict__ Sfg, const float* __restrict__ Pfg,
    const float* __restrict__ Scls,
    const short* __restrict__ Zrc, const float* __restrict__ Vc,
    const float* __restrict__ tiif, const float* __restrict__ tiic,
    const int* __restrict__ labels, const float* __restrict__ ious,
    int* __restrict__ cnt, float* __restrict__ accum, float* __restrict__ out) {
  int i = blockIdx.x * 256 + threadIdx.x;
  int l = labels[i];
  float iv = ious[i];
  float w = (iv > 0.5f) ? iv : 0.f;
  int cntP = 0;
  #pragma unroll
  for (int b = 2; b <= 21; ++b) cntP += cnt[b];
  int cntNI = N_ROI - cnt[0];
  bool Pi = (l > 0);
  float numF = 0.f, denF = 0.f, numC = 0.f, denC = 0.f;
  float eF = __expf(INV_TAU * tiif[i]);
  float Sf = Sfg[i] - eF;
  float Pf = Pfg[i] - (Pi ? eF : 0.f);
  int nposF = cntP - (Pi ? 1 : 0);
  if (Pi && nposF > 0) {
    float lossF = logf((Sf + 1e-8f) / (Pf + 1e-8f));
    numF = lossF * w; denF = w;
  }
  float tC = INV_TAU * tiic[i];
  float eC = __expf(tC);
  float Sc = Scls[i] - ((l != -1) ? eC : 0.f);
  // SP via class-sum decomposition: z_i . Vc[lab_i] * INV_TAU, minus self sim.
  float SPdot = 0.f;
  if (Pi) {
    const float* V = Vc + (size_t)(l - 1) * 128;
    int jt = i >> 5, r = i & 31;
    #pragma unroll
    for (int kc = 0; kc < 8; ++kc)
      #pragma unroll
      for (int h = 0; h < 2; ++h) {
        frag_ab z = *(const frag_ab*)&Zrc[((size_t)((jt * 8 + kc) * 64 + h * 32 + r)) * 8];
        #pragma unroll
        for (int e = 0; e < 8; ++e)
          SPdot += bf16_bits_to_f32(z[e]) * V[kc * 16 + h * 8 + e];
      }
  }
  float SP = SPdot * INV_TAU - (Pi ? tC : 0.f);
  int nposC = Pi ? (cnt[l + 1] - 1) : 0;
  bool anyv = (cntNI - ((l != -1) ? 1 : 0)) > 0;
  if (Pi && nposC > 0 && anyv) {
    float lse = logf(Sc);
    float lossC = -(SP - (float)nposC * lse) / fmaxf((float)nposC, 1.f);
    numC = lossC * w; denC = w;
  }
  float v0 = numF, v1 = denF, v2 = numC, v3 = denC;
  #pragma unroll
  for (int m = 1; m < 64; m <<= 1) {
    v0 += __shfl_xor(v0, m); v1 += __shfl_xor(v1, m);
    v2 += __shfl_xor(v2, m); v3 += __shfl_xor(v3, m);
  }
  __shared__ float red[4][4];
  int lane = threadIdx.x & 63, wid = threadIdx.x >> 6;
  if (lane == 0) { red[wid][0]=v0; red[wid][1]=v1; red[wid][2]=v2; red[wid][3]=v3; }
  __syncthreads();
  if (threadIdx.x == 0) {
    float s0=0,s1=0,s2=0,s3=0;
    for (int q = 0; q < 4; ++q) { s0+=red[q][0]; s1+=red[q][1]; s2+=red[q][2]; s3+=red[q][3]; }
    atomicAdd(&accum[0], s0); atomicAdd(&accum[1], s1);
    atomicAdd(&accum[2], s2); atomicAdd(&accum[3], s3);
    __threadfence();
    int t = atomicAdd(&cnt[22], 1);
    if (t == 31) {
      __threadfence();
      out[0] = accum[0] / (accum[1] + 1e-8f);
      out[1] = accum[2] / (accum[3] + 1e-12f);
    }
  }
}

extern "C" void kernel_launch(void* const* d_in, const int* in_sizes, int n_in,
                              void* d_out, int out_size, void* d_ws, size_t ws_size,
                              hipStream_t stream) {
  const float* X    = (const float*)d_in[0];
  const int*  labels= (const int*)d_in[1];
  const float* ious = (const float*)d_in[2];
  const float* w1f  = (const float*)d_in[3];
  const float* b1f  = (const float*)d_in[4];
  const float* w2f  = (const float*)d_in[5];
  const float* b2f  = (const float*)d_in[6];
  const float* w1c  = (const float*)d_in[7];
  const float* b1c  = (const float*)d_in[8];
  const float* w2c  = (const float*)d_in[9];
  const float* b2c  = (const float*)d_in[10];
  float* out = (float*)d_out;

  char* w = (char*)d_ws;
  short* W1pf = (short*)w;            w += 524288;
  short* W1pc = (short*)w;            w += 524288;
  short* W2pf = (short*)w;            w += 32768;
  short* W2pc = (short*)w;            w += 65536;
  short* Zrf  = (short*)w;            w += 1048576;
  short* Zrc  = (short*)w;            w += 2097152;
  float* Sfg  = (float*)w;            w += 32768;
  float* Pfg  = (float*)w;            w += 32768;
  float* Scls = (float*)w;            w += 32768;
  float* SPc  = (float*)w;            w += 32768;   // unused (kept for layout)
  float* tiif = (float*)w;            w += 32768;
  float* tiic = (float*)w;            w += 32768;
  float* pfv  = (float*)w;            w += 32768;
  float* nimv = (float*)w;            w += 32768;
  float* ljmv = (float*)w;            w += 32768;   // unused (kept for layout)
  float* accum= (float*)w;            w += 32;
  int*   cnt  = (int*)w;              w += 96;
  float* Vc   = (float*)w;            w += 10240;   // 20 classes x 128 dims f32
  short* Xp16 = (short*)w;            w += 16777216; // X in bf16 frag order
  (void)SPc; (void)ljmv;

  pack_zero_kernel<<<281 + 4096, 256, 0, stream>>>(X, w1f, w1c, w2f, w2c,
                                            W1pf, W1pc, W2pf, W2pc, Xp16,
                                            accum, cnt, Vc);

  fused_mlp_kernel<<<dim3(256, 2), 256, 0, stream>>>(Xp16, W1pf, W1pc, b1f, b1c,
                                            W2pf, W2pc, b2f, b2c,
                                            Zrf, Zrc, tiif, tiic,
                                            labels, Sfg, Pfg, Scls,
                                            pfv, nimv, cnt);

  loss_kernel<<<dim3(69, 16), 512, 0, stream>>>(Zrf, Zrc, labels, pfv, nimv,
                                                Sfg, Pfg, Scls, Vc);

  finalize_kernel<<<N_ROI/256, 256, 0, stream>>>(Sfg, Pfg, Scls, Zrc, Vc,
                                                 tiif, tiic,
                                                 labels, ious, cnt, accum, out);
}

// Round 10
// 187.434 us; speedup vs baseline: 1.1374x; 1.0405x over previous
//
#include <hip/hip_runtime.h>
#include <hip/hip_bf16.h>
#include <math.h>

#define N_ROI 8192
#define C_IN  1024
#define HIDD  256
#define FGD   64
#define CLSD  128
#define INV_TAU 5.0f
#define SCALE_LOG2E 7.2134752f   // 5 * log2(e)
#define LN2F 0.69314718f

using frag_ab = __attribute__((ext_vector_type(8))) short;   // 8 bf16 = 4 VGPRs
using f32x16  = __attribute__((ext_vector_type(16))) float;

static __device__ __forceinline__ short f32_to_bf16_bits(float f) {
  unsigned u = __builtin_bit_cast(unsigned, f);
  u = (u + 0x7FFFu + ((u >> 16) & 1u)) >> 16;   // RNE (inputs finite)
  return (short)u;
}
static __device__ __forceinline__ float bf16_bits_to_f32(short b) {
  unsigned u = ((unsigned)(unsigned short)b) << 16;
  return __builtin_bit_cast(float, u);
}
static __device__ __forceinline__ float fast_exp2(float x) {
#if __has_builtin(__builtin_amdgcn_exp2f)
  return __builtin_amdgcn_exp2f(x);
#else
  return exp2f(x);
#endif
}
// async global->LDS, 16B per lane. LDS dest = wave-uniform base + lane*16.
static __device__ __forceinline__ void async_copy16(const void* g, void* l) {
  __builtin_amdgcn_global_load_lds(
      (const __attribute__((address_space(1))) unsigned int*)g,
      (__attribute__((address_space(3))) unsigned int*)l, 16, 0, 0);
}

// ---------------- L1: pack weights + X (fp32 -> bf16 frag order) + zero ----------
// X pack (coalesced): Xp16[(Mb*32+c)*1024 + g*256 + r*8 + e] =
//   bf16(X[Mb*32+r][c*32 + g*8 + e])  — frag-order invariant preserved.
__global__ __launch_bounds__(256) void pack_zero_kernel(
    const float* __restrict__ X,
    const float* __restrict__ w1f, const float* __restrict__ w1c,
    const float* __restrict__ w2f, const float* __restrict__ w2c,
    short* __restrict__ W1pf, short* __restrict__ W1pc,
    short* __restrict__ W2pf, short* __restrict__ W2pc,
    short* __restrict__ Xp16,
    float* __restrict__ accum, int* __restrict__ cnt,
    float* __restrict__ Vc) {
  int b = blockIdx.x;
  if (b == 280) {
    int t = threadIdx.x;
    if (t < 8) accum[t] = 0.f;
    if (t < 24) cnt[t] = 0;
    for (int q = t; q < 2560; q += 256) Vc[q] = 0.f;
    return;
  }
  if (b >= 281) {                       // X pack: 4096 blocks, (Mb, cpair)
    int b2 = b - 281;
    int Mb = b2 >> 4, cpair = b2 & 15;
    int tid = threadIdx.x;
    int c = cpair * 2 + (tid >> 7);     // two col-tiles per block
    int tt = tid & 127;
    int r = tt >> 2;                    // row 0..31
    int g = tt & 3;                     // col-group 0..3 (8 cols each)
    const float* src = X + (size_t)(Mb * 32 + r) * C_IN + c * 32 + g * 8;
    float4 v0 = *(const float4*)src;
    float4 v1 = *(const float4*)(src + 4);
    union { short s[8]; uint4 v; } o;
    o.s[0] = f32_to_bf16_bits(v0.x); o.s[1] = f32_to_bf16_bits(v0.y);
    o.s[2] = f32_to_bf16_bits(v0.z); o.s[3] = f32_to_bf16_bits(v0.w);
    o.s[4] = f32_to_bf16_bits(v1.x); o.s[5] = f32_to_bf16_bits(v1.y);
    o.s[6] = f32_to_bf16_bits(v1.z); o.s[7] = f32_to_bf16_bits(v1.w);
    *(uint4*)&Xp16[((size_t)(Mb * 32 + c)) * 1024 + g * 256 + r * 8] = o.v;
    return;
  }
  const float* src; short* dst; int Ksh; int b0;
  if (b < 128)      { src = w1f; dst = W1pf; Ksh = 10; b0 = 0; }
  else if (b < 256) { src = w1c; dst = W1pc; Ksh = 10; b0 = 128; }
  else if (b < 264) { src = w2f; dst = W2pf; Ksh = 8;  b0 = 256; }
  else              { src = w2c; dst = W2pc; Ksh = 8;  b0 = 264; }
  int K = 1 << Ksh;
  int f = (b - b0) * 256 + threadIdx.x;
  int r = f >> (Ksh - 3);
  int c0 = (f & ((K >> 3) - 1)) << 3;
  float4 v0 = *(const float4*)(src + (size_t)r * K + c0);
  float4 v1 = *(const float4*)(src + (size_t)r * K + c0 + 4);
  union { short s[8]; uint4 v; } o;
  o.s[0] = f32_to_bf16_bits(v0.x); o.s[1] = f32_to_bf16_bits(v0.y);
  o.s[2] = f32_to_bf16_bits(v0.z); o.s[3] = f32_to_bf16_bits(v0.w);
  o.s[4] = f32_to_bf16_bits(v1.x); o.s[5] = f32_to_bf16_bits(v1.y);
  o.s[6] = f32_to_bf16_bits(v1.z); o.s[7] = f32_to_bf16_bits(v1.w);
  ((uint4*)dst)[(size_t)((r >> 5) * (K >> 4) + (c0 >> 4)) * 64 +
                ((c0 >> 3) & 1) * 32 + (r & 31)] = o.v;
}

// ---------------- phase-2: gemm2+normalize+pack — 4-WAVE PARALLEL ----------------
// Wave w computes column-tile w (cls: 4 active waves; fg: waves 0-1). Row-norm
// s1 and s2 are reduced per-wave then summed IN j-ORDER via LDS (sred): only a
// reassociation of fp32 adds vs the serial original. Z-gather split over k%4==w.
// Replaces the old single-wave tail (64 serial MFMA + transposes while 3 waves
// idled — half of each block's lifetime per the 14% occupancy signature).
template<int D>
__device__ __forceinline__ void gemm2_par(
    const short* __restrict__ T2,
    const short* __restrict__ W2p, const float* __restrict__ b2,
    short* __restrict__ Zr, float* __restrict__ tii,
    short* __restrict__ T, float* __restrict__ sred, int gt) {
  constexpr int NT = D / 32;            // 2 (fg) or 4 (cls)
  int tid = threadIdx.x, lane = tid & 63, wv = tid >> 6;
  int c = lane & 31, h = lane >> 5;
  bool act = (wv < NT);

  frag_ab a[16];
  f32x16 acc;
  float bb = 0.f;
  if (act) {
    #pragma unroll
    for (int kc = 0; kc < 16; ++kc)
      a[kc] = *(const frag_ab*)&T2[c * 264 + kc * 16 + h * 8];
    #pragma unroll
    for (int q = 0; q < 16; ++q) acc[q] = 0.f;
    const frag_ab* Wv = (const frag_ab*)W2p;
    #pragma unroll
    for (int kc = 0; kc < 16; ++kc)
      acc = __builtin_amdgcn_mfma_f32_32x32x16_bf16(a[kc], Wv[(wv * 16 + kc) * 64 + lane], acc, 0, 0, 0);
    bb = b2[wv * 32 + c];
    // per-wave partial s1 (this wave's col-tile contribution)
    float s1[16];
    #pragma unroll
    for (int r = 0; r < 16; ++r) { float v = acc[r] + bb; s1[r] = v * v; }
    #pragma unroll
    for (int r = 0; r < 16; ++r)
      #pragma unroll
      for (int m = 1; m < 32; m <<= 1) s1[r] += __shfl_xor(s1[r], m);
    if (c == 0) {                       // lanes 0 (h=0) and 32 (h=1)
      #pragma unroll
      for (int r = 0; r < 16; ++r) sred[(wv * 2 + h) * 16 + r] = s1[r];
    }
  }
  __syncthreads();
  // final s1: ordered j-sum (all waves compute the same value)
  float s1f[16];
  #pragma unroll
  for (int r = 0; r < 16; ++r) {
    float s = sred[h * 16 + r];
    #pragma unroll
    for (int j = 1; j < NT; ++j) s += sred[(j * 2 + h) * 16 + r];
    s1f[r] = s;
  }
  // normalize+pack this wave's col-tile; per-wave partial s2
  if (act) {
    float s2[16];
    #pragma unroll
    for (int r = 0; r < 16; ++r) s2[r] = 0.f;
    int cl = wv * 32 + c;
    #pragma unroll
    for (int g = 0; g < 4; ++g) {
      short q0, q1, q2, q3;
      #pragma unroll
      for (int e = 0; e < 4; ++e) {
        int r = g * 4 + e;
        float sc = 1.f / fmaxf(sqrtf(s1f[r]), 1e-8f);
        short qb = f32_to_bf16_bits((acc[r] + bb) * sc);
        float zf = bf16_bits_to_f32(qb);
        s2[r] += zf * zf;
        if (e == 0) q0 = qb; else if (e == 1) q1 = qb; else if (e == 2) q2 = qb; else q3 = qb;
      }
      *(short4*)&T[cl * 36 + 4 * h + 8 * g] = make_short4(q0, q1, q2, q3);
    }
    #pragma unroll
    for (int r = 0; r < 16; ++r)
      #pragma unroll
      for (int m = 1; m < 32; m <<= 1) s2[r] += __shfl_xor(s2[r], m);
    if (c == 0) {
      #pragma unroll
      for (int r = 0; r < 16; ++r) sred[128 + (wv * 2 + h) * 16 + r] = s2[r];
    }
  }
  __syncthreads();                      // T complete + sred2 ready
  if (wv == 0 && c == 0) {
    #pragma unroll
    for (int r = 0; r < 16; ++r) {
      float s = sred[128 + h * 16 + r];
      #pragma unroll
      for (int j = 1; j < NT; ++j) s += sred[128 + (j * 2 + h) * 16 + r];
      tii[gt * 32 + (r & 3) + 8 * (r >> 2) + 4 * h] = s;
    }
  }
  // Z gather: parallel over k (fg: k=wv for all 4 waves; cls: k=wv, wv+4)
  uint4* Zv = (uint4*)Zr;
  for (int k = wv; k < D / 16; k += 4) {
    int c0 = (2 * k + h) * 8;
    union { short s[8]; uint4 u; } o;
    #pragma unroll
    for (int e = 0; e < 8; ++e) o.s[e] = T[(c0 + e) * 36 + c];
    Zv[(size_t)(gt * (D / 16) + k) * 64 + h * 32 + c] = o.u;
  }
}

// ---------------- L2: fused MLP — A staged via global_load_lds ring (R6 k-loop) --
__global__ __launch_bounds__(256) void fused_mlp_kernel(
    const short* __restrict__ Xp16,
    const short* __restrict__ W1pf, const short* __restrict__ W1pc,
    const float* __restrict__ b1f, const float* __restrict__ b1c,
    const short* __restrict__ W2pf, const short* __restrict__ W2pc,
    const float* __restrict__ b2f, const float* __restrict__ b2c,
    short* __restrict__ Zrf, short* __restrict__ Zrc,
    float* __restrict__ tiif, float* __restrict__ tiic,
    const int* __restrict__ labels,
    float* __restrict__ Sfg, float* __restrict__ Pfg,
    float* __restrict__ Scls,
    float* __restrict__ pfv, float* __restrict__ nimv,
    int* __restrict__ cnt) {
  __shared__ short ringA[4 * 1024];     // 8 KB: 4-slot A ring (2KB/step)
  __shared__ short T2[32 * 264];        // 16.9 KB row-major H (this head)
  __shared__ short Tw[128 * 36];        // 9.2 KB phase-2 transpose
  __shared__ float sred[256];           // 1 KB phase-2 cross-wave reductions
  int tid = threadIdx.x, lane = tid & 63, wv = tid >> 6;
  int Mb = blockIdx.x, head = blockIdx.y;

  if (head == 0 && tid < 32) {
    int i = Mb * 32 + tid;
    Sfg[i] = 0.f; Pfg[i] = 0.f; Scls[i] = 0.f;
    int l = labels[i];
    pfv[i]  = (l > 0)  ? 1.f : 0.f;
    nimv[i] = (l != -1) ? 1.f : 0.f;
    int b = l + 1; if (b < 0) b = 0; if (b > 21) b = 21;
    atomicAdd(&cnt[b], 1);
  }
  // Drain prologue stores/atomics so vmcnt counting below is uniform & exact.
  __builtin_amdgcn_sched_barrier(0);
  asm volatile("s_waitcnt vmcnt(0)" ::: "memory");
  __builtin_amdgcn_sched_barrier(0);

  const short* Wp = head ? W1pc : W1pf;
  const float* b1 = head ? b1c  : b1f;
  const uint4* Wv4 = (const uint4*)Wp;
  int t127 = tid & 127;                 // waves 2,3 redundantly re-stage (uniform vmcnt)

  frag_ab breg[3][4];                   // 3 W banks = 2-step prefetch
  f32x16 acc[2];
  #pragma unroll
  for (int nt = 0; nt < 2; ++nt)
    #pragma unroll
    for (int q = 0; q < 16; ++q) acc[nt][q] = 0.f;

  auto stageA = [&](int c, int slot) {
    const short* src = Xp16 + ((size_t)(Mb * 32 + c)) * 1024 + (size_t)t127 * 8;
    async_copy16(src, &ringA[slot * 1024 + t127 * 8]);
  };
  auto loadB = [&](int c, int s) {
    #pragma unroll
    for (int kci = 0; kci < 2; ++kci)
      #pragma unroll
      for (int nt = 0; nt < 2; ++nt)
        breg[s][kci * 2 + nt] =
            *(const frag_ab*)&Wv4[(size_t)((wv * 2 + nt) * 64 + c * 2 + kci) * 64 + lane];
  };
  auto domfma = [&](int slot, int bank) {
    frag_ab a0 = *(const frag_ab*)&ringA[slot * 1024 + (0 * 64 + lane) * 8];
    frag_ab a1 = *(const frag_ab*)&ringA[slot * 1024 + (1 * 64 + lane) * 8];
    #pragma unroll
    for (int nt = 0; nt < 2; ++nt)
      acc[nt] = __builtin_amdgcn_mfma_f32_32x32x16_bf16(a0, breg[bank][nt], acc[nt], 0, 0, 0);
    #pragma unroll
    for (int nt = 0; nt < 2; ++nt)
      acc[nt] = __builtin_amdgcn_mfma_f32_32x32x16_bf16(a1, breg[bank][2 + nt], acc[nt], 0, 0, 0);
  };

  // prologue: A 3 slots ahead, B 2 banks ahead
  stageA(0, 0); stageA(1, 1); loadB(0, 0); stageA(2, 2); loadB(1, 1);

  #pragma unroll
  for (int c = 0; c < 32; ++c) {
    if (c < 30)       asm volatile("s_waitcnt vmcnt(5)" ::: "memory");
    else if (c == 30) asm volatile("s_waitcnt vmcnt(4)" ::: "memory");
    else              asm volatile("s_waitcnt vmcnt(0)" ::: "memory");
    __builtin_amdgcn_s_barrier();
    __builtin_amdgcn_sched_barrier(0);
    if (c + 3 < 32) stageA(c + 3, (c + 3) & 3);
    if (c + 2 < 32) loadB(c + 2, (c + 2) % 3);
    domfma(c & 3, c % 3);
  }
  {
    int cl31 = lane & 31, h = lane >> 5;
    #pragma unroll
    for (int nt = 0; nt < 2; ++nt) {
      int gc = wv * 64 + nt * 32 + cl31;
      float bb = b1[gc];
      #pragma unroll
      for (int q = 0; q < 16; ++q) {
        int row = (q & 3) + 8 * (q >> 2) + 4 * h;
        float x = fmaxf(acc[nt][q] + bb, 0.f);
        T2[row * 264 + gc] = f32_to_bf16_bits(x);
      }
    }
  }
  __syncthreads();

  if (head == 0)
    gemm2_par<FGD>(T2, W2pf, b2f, Zrf, tiif, Tw, sred, Mb);
  else
    gemm2_par<CLSD>(T2, W2pc, b2c, Zrc, tiic, Tw, sred, Mb);
}

// ---------------- L2b: per-class z-sums Vc (separate small dispatch, R6-proven) --
__global__ __launch_bounds__(128) void classsum_kernel(
    const short* __restrict__ Zrc, const int* __restrict__ labels,
    float* __restrict__ Vc) {
  __shared__ int lidx[512];
  __shared__ int lcnt;
  int c = blockIdx.x + 1;               // class 1..20
  int d = threadIdx.x;                  // dim 0..127
  int j0 = blockIdx.y * 512;
  if (d == 0) lcnt = 0;
  __syncthreads();
  #pragma unroll
  for (int u = 0; u < 4; ++u) {
    int row = j0 + u * 128 + d;
    if (labels[row] == c) {
      int k = atomicAdd(&lcnt, 1);
      lidx[k] = row;
    }
  }
  __syncthreads();
  int n = lcnt;
  int kc = d >> 4, h = (d >> 3) & 1, e = d & 7;
  float acc = 0.f;
  for (int k = 0; k < n; ++k) {
    int row = lidx[k];
    int jt = row >> 5, r = row & 31;
    acc += bf16_bits_to_f32(
        Zrc[((size_t)((jt * 8 + kc) * 64 + h * 32 + r)) * 8 + e]);
  }
  atomicAdd(&Vc[(c - 1) * 128 + d], acc);
}

// ---------------- L3: MFMA Gram loss — full Gram, JP=2, cls Psum removed ---------
template<int D, int MODE, int NJT>
__device__ __forceinline__ void loss_body(
    const short* __restrict__ Zr,
    const float* __restrict__ maskv,
    float* __restrict__ Sg, float* __restrict__ Pg,
    short* __restrict__ smem) {
  constexpr int KC = D / 16;              // 4 (fg) or 8 (cls)
  constexpr int JP = 2;
  constexpr int NIT = NJT / JP;           // 8
  constexpr int BUFQ = JP * KC * 512;     // shorts per buffer (fg 4096, cls 8192)
  constexpr int LD = BUFQ / 4096;         // async copies per wave per STAGE (1/2)
  int tid = threadIdx.x, lane = tid & 63, wv = tid >> 6;   // wv in 0..7
  int itile = (blockIdx.x >> 1) * 8 + wv;
  int jt0 = blockIdx.y * NJT;
  int jlane = lane & 31;
  const frag_ab* Zrv = (const frag_ab*)Zr;

  // A fragments (rescaled to log2-domain)
  frag_ab a[KC];
  #pragma unroll
  for (int kc = 0; kc < KC; ++kc) {
    frag_ab t = Zrv[(itile * KC + kc) * 64 + lane];
    #pragma unroll
    for (int e = 0; e < 8; ++e)
      t[e] = f32_to_bf16_bits(bf16_bits_to_f32(t[e]) * SCALE_LOG2E);
    a[kc] = t;
  }
  // Pin prologue register loads before the drain so later vmcnt counts are exact.
  __builtin_amdgcn_sched_barrier(0);
  asm volatile("s_waitcnt vmcnt(0)" ::: "memory");
  __builtin_amdgcn_sched_barrier(0);

  short* b0 = smem;
  short* b1 = smem + BUFQ;
  short* b2 = smem + 2 * BUFQ;
  float* maskf = (float*)(smem + 3 * BUFQ);   // NJT*32 = 512 floats

  // stage mask: exactly 1 global_load_lds per wave (waves 2-7 redundant)
  async_copy16(maskv + jt0 * 32 + (size_t)(tid & 127) * 4,
               maskf + (wv & 1) * 256);

  auto STAGE = [&](short* dst, int it) {
    const short* src = Zr + (size_t)(jt0 + it * JP) * KC * 512;
    #pragma unroll
    for (int u = 0; u < LD; ++u)
      async_copy16(src + (size_t)(u * 512 + tid) * 8, dst + u * 4096 + wv * 512);
  };

  STAGE(b0, 0); STAGE(b1, 1);

  float Ssum[16] = {}, Psum[16] = {};

  #pragma unroll 1
  for (int t = 0; t < NIT; ++t) {
    if (t < NIT - 1) {
      if constexpr (LD == 1) asm volatile("s_waitcnt vmcnt(1)" ::: "memory");
      else                   asm volatile("s_waitcnt vmcnt(2)" ::: "memory");
    } else {
      asm volatile("s_waitcnt vmcnt(0)" ::: "memory");
    }
    __builtin_amdgcn_s_barrier();
    __builtin_amdgcn_sched_barrier(0);
    if (t + 2 < NIT) STAGE(b2, t + 2);

    float m0 = maskf[t * 64 + jlane];
    float m1 = maskf[t * 64 + 32 + jlane];
    f32x16 acc0, acc1;
    #pragma unroll
    for (int q = 0; q < 16; ++q) { acc0[q] = 0.f; acc1[q] = 0.f; }
    #pragma unroll
    for (int kc = 0; kc < KC; ++kc) {
      frag_ab bb0 = *(const frag_ab*)&b0[(kc * 64 + lane) * 8];
      frag_ab bb1 = *(const frag_ab*)&b0[((KC + kc) * 64 + lane) * 8];
      acc0 = __builtin_amdgcn_mfma_f32_32x32x16_bf16(a[kc], bb0, acc0, 0, 0, 0);
      acc1 = __builtin_amdgcn_mfma_f32_32x32x16_bf16(a[kc], bb1, acc1, 0, 0, 0);
    }
    #pragma unroll
    for (int rr = 0; rr < 16; ++rr) {
      float e0 = fast_exp2(acc0[rr]);
      float e1 = fast_exp2(acc1[rr]);
      if (MODE == 0) {
        Ssum[rr] += e0 + e1;
        Psum[rr] = fmaf(m0, e0, fmaf(m1, e1, Psum[rr]));
      } else {
        Ssum[rr] = fmaf(m1, e1, fmaf(m0, e0, Ssum[rr]));
      }
    }
    short* tmp = b0; b0 = b1; b1 = b2; b2 = tmp;   // rotate
  }

  #pragma unroll
  for (int r = 0; r < 16; ++r) {
    float s = Ssum[r], p = Psum[r];
    #pragma unroll
    for (int m = 1; m < 32; m <<= 1) {
      s += __shfl_xor(s, m);
      if (MODE == 0) p += __shfl_xor(p, m);
    }
    if ((lane & 31) == 0) {
      int rw = (r & 3) + 8 * (r >> 2) + 4 * (lane >> 5);
      atomicAdd(&Sg[itile * 32 + rw], s);
      if (MODE == 0) atomicAdd(&Pg[itile * 32 + rw], p);
    }
  }
}

__global__ __launch_bounds__(512, 2) void loss_kernel(
    const short* __restrict__ Zrf, const short* __restrict__ Zrc,
    const float* __restrict__ pfv, const float* __restrict__ nimv,
    float* __restrict__ Sfg, float* __restrict__ Pfg,
    float* __restrict__ Scls) {
  // 3 x 16 KB rotating buffers (cls size) + mask region = 50 KB
  __shared__ short smem[3 * 8192 + 1024];
  if ((blockIdx.x & 1) == 0)
    loss_body<FGD, 0, 16>(Zrf, pfv, Sfg, Pfg, smem);
  else
    loss_body<CLSD, 1, 16>(Zrc, nimv, Scls, nullptr, smem);
}

// ---------------- L4: per-row losses + weighted reduction + write-out ------------
__global__ __launch_bounds__(256) void finalize_kernel(
    const float* __restrict__ Sfg, const float* __restrict__ Pfg,
    const float* __restrict__ Scls,
    const short* __restrict__ Zrc, const float* __restrict__ Vc,
    const float* __restrict__ tiif, const float* __restrict__ tiic,
    const int* __restrict__ labels, const float* __restrict__ ious,
    int* __restrict__ cnt, float* __restrict__ accum, float* __restrict__ out) {
  int i = blockIdx.x * 256 + threadIdx.x;
  int l = labels[i];
  float iv = ious[i];
  float w = (iv > 0.5f) ? iv : 0.f;
  int cntP = 0;
  #pragma unroll
  for (int b = 2; b <= 21; ++b) cntP += cnt[b];
  int cntNI = N_ROI - cnt[0];
  bool Pi = (l > 0);
  float numF = 0.f, denF = 0.f, numC = 0.f, denC = 0.f;
  float eF = __expf(INV_TAU * tiif[i]);
  float Sf = Sfg[i] - eF;
  float Pf = Pfg[i] - (Pi ? eF : 0.f);
  int nposF = cntP - (Pi ? 1 : 0);
  if (Pi && nposF > 0) {
    float lossF = logf((Sf + 1e-8f) / (Pf + 1e-8f));
    numF = lossF * w; denF = w;
  }
  float tC = INV_TAU * tiic[i];
  float eC = __expf(tC);
  float Sc = Scls[i] - ((l != -1) ? eC : 0.f);
  // SP via class-sum decomposition: z_i . Vc[lab_i] * INV_TAU, minus self sim.
  float SPdot = 0.f;
  if (Pi) {
    const float* V = Vc + (size_t)(l - 1) * 128;
    int jt = i >> 5, r = i & 31;
    #pragma unroll
    for (int kc = 0; kc < 8; ++kc)
      #pragma unroll
      for (int h = 0; h < 2; ++h) {
        frag_ab z = *(const frag_ab*)&Zrc[((size_t)((jt * 8 + kc) * 64 + h * 32 + r)) * 8];
        #pragma unroll
        for (int e = 0; e < 8; ++e)
          SPdot += bf16_bits_to_f32(z[e]) * V[kc * 16 + h * 8 + e];
      }
  }
  float SP = SPdot * INV_TAU - (Pi ? tC : 0.f);
  int nposC = Pi ? (cnt[l + 1] - 1) : 0;
  bool anyv = (cntNI - ((l != -1) ? 1 : 0)) > 0;
  if (Pi && nposC > 0 && anyv) {
    float lse = logf(Sc);
    float lossC = -(SP - (float)nposC * lse) / fmaxf((float)nposC, 1.f);
    numC = lossC * w; denC = w;
  }
  float v0 = numF, v1 = denF, v2 = numC, v3 = denC;
  #pragma unroll
  for (int m = 1; m < 64; m <<= 1) {
    v0 += __shfl_xor(v0, m); v1 += __shfl_xor(v1, m);
    v2 += __shfl_xor(v2, m); v3 += __shfl_xor(v3, m);
  }
  __shared__ float red[4][4];
  int lane = threadIdx.x & 63, wid = threadIdx.x >> 6;
  if (lane == 0) { red[wid][0]=v0; red[wid][1]=v1; red[wid][2]=v2; red[wid][3]=v3; }
  __syncthreads();
  if (threadIdx.x == 0) {
    float s0=0,s1=0,s2=0,s3=0;
    for (int q = 0; q < 4; ++q) { s0+=red[q][0]; s1+=red[q][1]; s2+=red[q][2]; s3+=red[q][3]; }
    atomicAdd(&accum[0], s0); atomicAdd(&accum[1], s1);
    atomicAdd(&accum[2], s2); atomicAdd(&accum[3], s3);
    __threadfence();
    int t = atomicAdd(&cnt[22], 1);
    if (t == 31) {
      __threadfence();
      out[0] = accum[0] / (accum[1] + 1e-8f);
      out[1] = accum[2] / (accum[3] + 1e-12f);
    }
  }
}

extern "C" void kernel_launch(void* const* d_in, const int* in_sizes, int n_in,
                              void* d_out, int out_size, void* d_ws, size_t ws_size,
                              hipStream_t stream) {
  const float* X    = (const float*)d_in[0];
  const int*  labels= (const int*)d_in[1];
  const float* ious = (const float*)d_in[2];
  const float* w1f  = (const float*)d_in[3];
  const float* b1f  = (const float*)d_in[4];
  const float* w2f  = (const float*)d_in[5];
  const float* b2f  = (const float*)d_in[6];
  const float* w1c  = (const float*)d_in[7];
  const float* b1c  = (const float*)d_in[8];
  const float* w2c  = (const float*)d_in[9];
  const float* b2c  = (const float*)d_in[10];
  float* out = (float*)d_out;

  char* w = (char*)d_ws;
  short* W1pf = (short*)w;            w += 524288;
  short* W1pc = (short*)w;            w += 524288;
  short* W2pf = (short*)w;            w += 32768;
  short* W2pc = (short*)w;            w += 65536;
  short* Zrf  = (short*)w;            w += 1048576;
  short* Zrc  = (short*)w;            w += 2097152;
  float* Sfg  = (float*)w;            w += 32768;
  float* Pfg  = (float*)w;            w += 32768;
  float* Scls = (float*)w;            w += 32768;
  float* SPc  = (float*)w;            w += 32768;   // unused (kept for layout)
  float* tiif = (float*)w;            w += 32768;
  float* tiic = (float*)w;            w += 32768;
  float* pfv  = (float*)w;            w += 32768;
  float* nimv = (float*)w;            w += 32768;
  float* ljmv = (float*)w;            w += 32768;   // unused (kept for layout)
  float* accum= (float*)w;            w += 32;
  int*   cnt  = (int*)w;              w += 96;
  float* Vc   = (float*)w;            w += 10240;   // 20 classes x 128 dims f32
  short* Xp16 = (short*)w;            w += 16777216; // X in bf16 frag order
  (void)SPc; (void)ljmv;

  pack_zero_kernel<<<281 + 4096, 256, 0, stream>>>(X, w1f, w1c, w2f, w2c,
                                            W1pf, W1pc, W2pf, W2pc, Xp16,
                                            accum, cnt, Vc);

  fused_mlp_kernel<<<dim3(256, 2), 256, 0, stream>>>(Xp16, W1pf, W1pc, b1f, b1c,
                                            W2pf, W2pc, b2f, b2c,
                                            Zrf, Zrc, tiif, tiic,
                                            labels, Sfg, Pfg, Scls,
                                            pfv, nimv, cnt);

  classsum_kernel<<<dim3(20, 16), 128, 0, stream>>>(Zrc, labels, Vc);

  loss_kernel<<<dim3(64, 16), 512, 0, stream>>>(Zrf, Zrc, pfv, nimv,
                                                Sfg, Pfg, Scls);

  finalize_kernel<<<N_ROI/256, 256, 0, stream>>>(Sfg, Pfg, Scls, Zrc, Vc,
                                                 tiif, tiic,
                                                 labels, ious, cnt, accum, out);
}